// Round 2
// baseline (2408.830 us; speedup 1.0000x reference)
//
#include <hip/hip_runtime.h>
#include <math.h>

#define Bn 8
#define Cn 64
#define Hn 96
#define Wn 96
#define HWn (Hn*Wn)
#define OCn 64
#define Kn 9
#define OFFCn 27
#define NPIX (Bn*HWn)        // 73728 = 1152 * 64
#define BLKS (NPIX/64)       // 1152 blocks, 64 pixels each
#define BLK_PER_B (HWn/64)   // 144 blocks per batch image

// LDS reused: phase1 partials need 4*64*27=6912 floats; phase2 s needs 16*9*64=9216.
#define LDSF (16*9*64)

__global__ __launch_bounds__(256, 4) void dcn_fused(
    const float* __restrict__ x,
    const float* __restrict__ w_off,
    const float* __restrict__ b_off,
    const float* __restrict__ weight,
    const float* __restrict__ bias,
    float* __restrict__ out)
{
    __shared__ float lds[LDSF];

    const int tid  = threadIdx.x;
    const int lane = tid & 63;       // pixel within block
    const int wv   = tid >> 6;       // wave id 0..3

    // XCD swizzle: 1152 blocks = 8 XCDs * 144; one full batch image per XCD
    // -> per-XCD gather working set = 2.36 MB < 4 MiB L2.
    const int bid = (blockIdx.x & 7) * BLK_PER_B + (blockIdx.x >> 3);

    const int p  = bid * 64 + lane;
    const int b  = p / HWn;
    const int hw = p % HWn;
    const int ho = hw / Wn;
    const int wo = hw % Wn;

    const float* xb = x + b * (Cn * HWn);

    // ---- static 3x3 taps (zero-pad via multiply, branchless, uniform CF) ----
    int   toff[Kn];
    float tval[Kn];
#pragma unroll
    for (int ki = 0; ki < Kn; ++ki) {
        const int yy = ho + ki / 3 - 1, xx = wo + ki % 3 - 1;
        const bool v = (yy >= 0) && (yy < Hn) && (xx >= 0) && (xx < Wn);
        toff[ki] = min(max(yy, 0), Hn - 1) * Wn + min(max(xx, 0), Wn - 1);
        tval[ki] = v ? 1.0f : 0.0f;
    }

    // ---------------- Phase 1: offset conv, c-split across 4 waves ----------------
    float om[OFFCn];
#pragma unroll
    for (int j = 0; j < OFFCn; ++j) om[j] = 0.0f;

    for (int ci = 0; ci < 16; ++ci) {
        const int c = wv * 16 + ci;
        const float* xc = xb + c * HWn;
        float xk[Kn];
#pragma unroll
        for (int ki = 0; ki < Kn; ++ki)
            xk[ki] = xc[toff[ki]] * tval[ki];

        const float* wc = w_off + c * Kn;          // w_off[och][c][0..8]
#pragma unroll
        for (int och = 0; och < OFFCn; ++och) {
            const float* wp = wc + och * (Cn * Kn);
            float a = om[och];
#pragma unroll
            for (int ki = 0; ki < Kn; ++ki)
                a = fmaf(xk[ki], wp[ki], a);
            om[och] = a;
        }
    }

    // partial write: stride 27 dwords, gcd(27,32)=1 -> conflict-free
#pragma unroll
    for (int j = 0; j < OFFCn; ++j)
        lds[(wv * 64 + lane) * OFFCn + j] = om[j];
    __syncthreads();
#pragma unroll
    for (int j = 0; j < OFFCn; ++j) {
        float a = b_off[j];
#pragma unroll
        for (int ww = 0; ww < 4; ++ww)
            a += lds[(ww * 64 + lane) * OFFCn + j];
        om[j] = a;
    }
    __syncthreads();   // lds will be reused for samples

    // ---------------- Phase 1.5: per-k sampling params (all waves, own pixel) ----
    float pw0[Kn], pw1[Kn], pw2[Kn], pw3[Kn];
    int   pa[Kn], pdx[Kn], pdyw[Kn];
#pragma unroll
    for (int ki = 0; ki < Kn; ++ki) {
        const float py = om[ki]          + (float)(ki / 3 + ho - 1);
        const float px = om[Kn + ki]     + (float)(ki % 3 + wo - 1);
        const float m  = 1.0f / (1.0f + __expf(-om[2 * Kn + ki]));

        const float y0f = floorf(py), x0f = floorf(px);
        const float ly = py - y0f, lx = px - x0f;
        const int iy0 = (int)y0f, ix0 = (int)x0f;
        const int iy1 = iy0 + 1,  ix1 = ix0 + 1;

        const float vy0 = (iy0 >= 0 && iy0 < Hn) ? 1.0f : 0.0f;
        const float vy1 = (iy1 >= 0 && iy1 < Hn) ? 1.0f : 0.0f;
        const float vx0 = (ix0 >= 0 && ix0 < Wn) ? 1.0f : 0.0f;
        const float vx1 = (ix1 >= 0 && ix1 < Wn) ? 1.0f : 0.0f;

        const int iy0c = min(max(iy0, 0), Hn - 1);
        const int iy1c = min(max(iy1, 0), Hn - 1);
        const int ix0c = min(max(ix0, 0), Wn - 1);
        const int ix1c = min(max(ix1, 0), Wn - 1);

        pw0[ki] = m * (1.0f - ly) * (1.0f - lx) * vy0 * vx0;
        pw1[ki] = m * (1.0f - ly) * lx          * vy0 * vx1;
        pw2[ki] = m * ly          * (1.0f - lx) * vy1 * vx0;
        pw3[ki] = m * ly          * lx          * vy1 * vx1;
        pa[ki]   = iy0c * Wn + ix0c;
        pdx[ki]  = ix1c - ix0c;            // 0 or 1
        pdyw[ki] = (iy1c - iy0c) * Wn;     // 0 or Wn
    }

    // ---------------- Phase 2: cooperative gather + 16-OC contraction ----------
    float acc[16];
#pragma unroll
    for (int j = 0; j < 16; ++j) acc[j] = bias[wv * 16 + j];

    for (int ch = 0; ch < 4; ++ch) {
        // gather 16 channels (4 per wave) for own pixel into lds[c16][k][pix]
#pragma unroll
        for (int cc = 0; cc < 4; ++cc) {
            const int cl = wv * 4 + cc;
            const float* xc = xb + (ch * 16 + cl) * HWn;
#pragma unroll
            for (int ki = 0; ki < Kn; ++ki) {
                const float* bp = xc + pa[ki];
                const float v00 = bp[0];
                const float v01 = bp[pdx[ki]];
                const float v10 = bp[pdyw[ki]];
                const float v11 = bp[pdyw[ki] + pdx[ki]];
                lds[(cl * Kn + ki) * 64 + lane] =
                    pw0[ki] * v00 + pw1[ki] * v01 + pw2[ki] * v10 + pw3[ki] * v11;
            }
        }
        __syncthreads();

        // each wave: 16 output channels, 16 c * 9 k FMAs each
        const float* wch = weight + (wv * 16) * (Cn * Kn) + (ch * 16) * Kn;
#pragma unroll 4
        for (int c16 = 0; c16 < 16; ++c16) {
            float sv[Kn];
#pragma unroll
            for (int ki = 0; ki < Kn; ++ki)
                sv[ki] = lds[(c16 * Kn + ki) * 64 + lane];
#pragma unroll
            for (int oc16 = 0; oc16 < 16; ++oc16) {
                const float* wp = wch + oc16 * (Cn * Kn) + c16 * Kn;
                float a = acc[oc16];
#pragma unroll
                for (int ki = 0; ki < Kn; ++ki)
                    a = fmaf(sv[ki], wp[ki], a);
                acc[oc16] = a;
            }
        }
        __syncthreads();
    }

    // ---------------- Store: out[b][oc][hw], lanes contiguous in hw ------------
    float* ob = out + b * (OCn * HWn) + (wv * 16) * HWn + hw;
#pragma unroll
    for (int j = 0; j < 16; ++j)
        ob[j * HWn] = acc[j];
}

extern "C" void kernel_launch(void* const* d_in, const int* in_sizes, int n_in,
                              void* d_out, int out_size, void* d_ws, size_t ws_size,
                              hipStream_t stream) {
    const float* x      = (const float*)d_in[0];
    const float* w_off  = (const float*)d_in[1];
    const float* b_off  = (const float*)d_in[2];
    const float* weight = (const float*)d_in[3];
    const float* bias   = (const float*)d_in[4];
    float* out = (float*)d_out;

    hipLaunchKernelGGL(dcn_fused, dim3(BLKS), dim3(256), 0, stream,
                       x, w_off, b_off, weight, bias, out);
}

// Round 3
// 878.455 us; speedup vs baseline: 2.7421x; 2.7421x over previous
//
#include <hip/hip_runtime.h>
#include <math.h>

#define Bn 8
#define Cn 64
#define Hn 96
#define Wn 96
#define HWn (Hn*Wn)
#define OCn 64
#define Kn 9
#define OFFCn 27
#define NPIX (Bn*HWn)        // 73728 = 1152 * 64
#define BLKS (NPIX/64)       // 1152 blocks, 64 pixels each
#define BLK_PER_B (HWn/64)   // 144 blocks per batch image

// LDS reused: phase1 partials need 4*64*27=6912 floats; phase2 s needs 16*9*64=9216.
#define LDSF (16*9*64)

// NOTE R2 post-mortem: __launch_bounds__(256,4) clamped VGPR to 64 -> massive
// scratch spills (6.2 GB HBM traffic). (256,2) caps at 256 VGPR; live state
// needs ~110, which still allows 4 waves/SIMD (VGPR<=128).
__global__ __launch_bounds__(256, 2) void dcn_fused(
    const float* __restrict__ x,
    const float* __restrict__ w_off,
    const float* __restrict__ b_off,
    const float* __restrict__ weight,
    const float* __restrict__ bias,
    float* __restrict__ out)
{
    __shared__ float lds[LDSF];

    const int tid  = threadIdx.x;
    const int lane = tid & 63;       // pixel within block
    const int wv   = tid >> 6;       // wave id 0..3

    // XCD swizzle: 1152 blocks = 8 XCDs * 144; one full batch image per XCD
    // -> per-XCD gather working set = 2.36 MB < 4 MiB L2.
    const int bid = (blockIdx.x & 7) * BLK_PER_B + (blockIdx.x >> 3);

    const int p  = bid * 64 + lane;
    const int b  = p / HWn;
    const int hw = p % HWn;
    const int ho = hw / Wn;
    const int wo = hw % Wn;

    const float* xb = x + b * (Cn * HWn);

    // ---- static 3x3 taps (zero-pad via multiply, branchless, uniform CF) ----
    int   toff[Kn];
    float tval[Kn];
#pragma unroll
    for (int ki = 0; ki < Kn; ++ki) {
        const int yy = ho + ki / 3 - 1, xx = wo + ki % 3 - 1;
        const bool v = (yy >= 0) && (yy < Hn) && (xx >= 0) && (xx < Wn);
        toff[ki] = min(max(yy, 0), Hn - 1) * Wn + min(max(xx, 0), Wn - 1);
        tval[ki] = v ? 1.0f : 0.0f;
    }

    // ---------------- Phase 1: offset conv, c-split across 4 waves ----------------
    float om[OFFCn];
#pragma unroll
    for (int j = 0; j < OFFCn; ++j) om[j] = 0.0f;

    for (int ci = 0; ci < 16; ++ci) {
        const int c = wv * 16 + ci;
        const float* xc = xb + c * HWn;
        float xk[Kn];
#pragma unroll
        for (int ki = 0; ki < Kn; ++ki)
            xk[ki] = xc[toff[ki]] * tval[ki];

        const float* wc = w_off + c * Kn;          // w_off[och][c][0..8]
#pragma unroll
        for (int och = 0; och < OFFCn; ++och) {
            const float* wp = wc + och * (Cn * Kn);
            float a = om[och];
#pragma unroll
            for (int ki = 0; ki < Kn; ++ki)
                a = fmaf(xk[ki], wp[ki], a);
            om[och] = a;
        }
    }

    // partial write: stride 27 dwords, gcd(27,32)=1 -> conflict-free
#pragma unroll
    for (int j = 0; j < OFFCn; ++j)
        lds[(wv * 64 + lane) * OFFCn + j] = om[j];
    __syncthreads();
#pragma unroll
    for (int j = 0; j < OFFCn; ++j) {
        float a = b_off[j];
#pragma unroll
        for (int ww = 0; ww < 4; ++ww)
            a += lds[(ww * 64 + lane) * OFFCn + j];
        om[j] = a;
    }
    __syncthreads();   // lds will be reused for samples

    // ---------------- Phase 1.5: per-k sampling params (all waves, own pixel) ----
    float pw0[Kn], pw1[Kn], pw2[Kn], pw3[Kn];
    int   pa[Kn], pdx[Kn], pdyw[Kn];
#pragma unroll
    for (int ki = 0; ki < Kn; ++ki) {
        const float py = om[ki]          + (float)(ki / 3 + ho - 1);
        const float px = om[Kn + ki]     + (float)(ki % 3 + wo - 1);
        const float m  = 1.0f / (1.0f + __expf(-om[2 * Kn + ki]));

        const float y0f = floorf(py), x0f = floorf(px);
        const float ly = py - y0f, lx = px - x0f;
        const int iy0 = (int)y0f, ix0 = (int)x0f;
        const int iy1 = iy0 + 1,  ix1 = ix0 + 1;

        const float vy0 = (iy0 >= 0 && iy0 < Hn) ? 1.0f : 0.0f;
        const float vy1 = (iy1 >= 0 && iy1 < Hn) ? 1.0f : 0.0f;
        const float vx0 = (ix0 >= 0 && ix0 < Wn) ? 1.0f : 0.0f;
        const float vx1 = (ix1 >= 0 && ix1 < Wn) ? 1.0f : 0.0f;

        const int iy0c = min(max(iy0, 0), Hn - 1);
        const int iy1c = min(max(iy1, 0), Hn - 1);
        const int ix0c = min(max(ix0, 0), Wn - 1);
        const int ix1c = min(max(ix1, 0), Wn - 1);

        pw0[ki] = m * (1.0f - ly) * (1.0f - lx) * vy0 * vx0;
        pw1[ki] = m * (1.0f - ly) * lx          * vy0 * vx1;
        pw2[ki] = m * ly          * (1.0f - lx) * vy1 * vx0;
        pw3[ki] = m * ly          * lx          * vy1 * vx1;
        pa[ki]   = iy0c * Wn + ix0c;
        pdx[ki]  = ix1c - ix0c;            // 0 or 1
        pdyw[ki] = (iy1c - iy0c) * Wn;     // 0 or Wn
    }

    // ---------------- Phase 2: cooperative gather + 16-OC contraction ----------
    float acc[16];
#pragma unroll
    for (int j = 0; j < 16; ++j) acc[j] = bias[wv * 16 + j];

    for (int ch = 0; ch < 4; ++ch) {
        // gather 16 channels (4 per wave) for own pixel into lds[c16][k][pix]
#pragma unroll
        for (int cc = 0; cc < 4; ++cc) {
            const int cl = wv * 4 + cc;
            const float* xc = xb + (ch * 16 + cl) * HWn;
#pragma unroll
            for (int ki = 0; ki < Kn; ++ki) {
                const float* bp = xc + pa[ki];
                const float v00 = bp[0];
                const float v01 = bp[pdx[ki]];
                const float v10 = bp[pdyw[ki]];
                const float v11 = bp[pdyw[ki] + pdx[ki]];
                lds[(cl * Kn + ki) * 64 + lane] =
                    pw0[ki] * v00 + pw1[ki] * v01 + pw2[ki] * v10 + pw3[ki] * v11;
            }
        }
        __syncthreads();

        // each wave: 16 output channels, 16 c * 9 k FMAs each
        const float* wch = weight + (wv * 16) * (Cn * Kn) + (ch * 16) * Kn;
#pragma unroll 4
        for (int c16 = 0; c16 < 16; ++c16) {
            float sv[Kn];
#pragma unroll
            for (int ki = 0; ki < Kn; ++ki)
                sv[ki] = lds[(c16 * Kn + ki) * 64 + lane];
#pragma unroll
            for (int oc16 = 0; oc16 < 16; ++oc16) {
                const float* wp = wch + oc16 * (Cn * Kn) + c16 * Kn;
                float a = acc[oc16];
#pragma unroll
                for (int ki = 0; ki < Kn; ++ki)
                    a = fmaf(sv[ki], wp[ki], a);
                acc[oc16] = a;
            }
        }
        __syncthreads();
    }

    // ---------------- Store: out[b][oc][hw], lanes contiguous in hw ------------
    float* ob = out + b * (OCn * HWn) + (wv * 16) * HWn + hw;
#pragma unroll
    for (int j = 0; j < 16; ++j)
        ob[j * HWn] = acc[j];
}

extern "C" void kernel_launch(void* const* d_in, const int* in_sizes, int n_in,
                              void* d_out, int out_size, void* d_ws, size_t ws_size,
                              hipStream_t stream) {
    const float* x      = (const float*)d_in[0];
    const float* w_off  = (const float*)d_in[1];
    const float* b_off  = (const float*)d_in[2];
    const float* weight = (const float*)d_in[3];
    const float* bias   = (const float*)d_in[4];
    float* out = (float*)d_out;

    hipLaunchKernelGGL(dcn_fused, dim3(BLKS), dim3(256), 0, stream,
                       x, w_off, b_off, weight, bias, out);
}